// Round 3
// baseline (789.765 us; speedup 1.0000x reference)
//
#include <hip/hip_runtime.h>

// Batched box-QP via ADMM (rho=1, 50 iters), one 1024-thread workgroup per batch.
// M = Q + I (SPD, cond~3) inverted in LDS by a RANK-8 blocked symmetric sweep on
// the packed quad-padded lower triangle. Each of 528 threads owns one 8x8 region
// (2x2 tiles). Pivot-block 8x8 inverse computed by wave 0 (lane-per-element,
// shfl), panels stored transposed + XOR-swizzled for conflict-free reads.
// Iterations: Minv row chunks pinned in VGPRs, rhs broadcast from padded LDS.

#define NX     256
#define NITER  50
#define TRIF   33280   // padded packed-triangle floats
#define NTHR   1024
#define NREG   528     // 32*33/2 8x8 regions
#define PTF    264     // floats per P_T/W_T row (66 quads)

// float offsets in LDS
#define OFF_PT  33280
#define OFF_WT  35392
#define OFF_W8  37504
#define OFF_SL  39552
#define OFF_VB  39632
#define LDS_F   39904   // total floats (159616 B)

__device__ __forceinline__ int rowoff(int r) {      // packed row offset (floats)
    int M = r >> 2, s = r & 3;
    return 4 * (M + 1) * ((M << 1) + s);
}
__device__ __forceinline__ int physq(int q) { return q ^ ((q >> 3) & 7); }
__device__ __forceinline__ int physf(int i) { return 4 * physq(i >> 2) + (i & 3); }

__launch_bounds__(NTHR, 4)
__global__ void boxqp_r8_kernel(const float* __restrict__ Q,
                                const float* __restrict__ p,
                                const float* __restrict__ lb,
                                const float* __restrict__ ub,
                                float* __restrict__ out)
{
    extern __shared__ float lds[];
    float*  tri  = lds;
    float4* tri4 = (float4*)tri;
    float*  PT   = lds + OFF_PT;   // P transposed [8][PTF], XOR-swizzled floats
    float*  WT   = lds + OFF_WT;   // W transposed [8][PTF], linear
    float*  W8   = lds + OFF_W8;   // W row-major  [256][8]
    float*  SL   = lds + OFF_SL;   // swept pivot block [8][9]
    float*  vbuf = lds + OFF_VB;   // rhs broadcast, 4 chunks of 68

    const int t = threadIdx.x;
    const int b = blockIdx.x;
    const size_t qbase = ((size_t)b) << 16;   // b*256*256

    // --- per-thread region coordinates (valid for t < NREG) ---
    int rb2, cb2;
    {
        int tt = (t < NREG) ? t : 0;
        int r_ = (int)((sqrtf((float)(8 * tt + 1)) - 1.0f) * 0.5f);
        while ((r_ + 1) * (r_ + 2) / 2 <= tt) ++r_;
        while (r_ * (r_ + 1) / 2 > tt) --r_;
        rb2 = r_;
        cb2 = tt - ((r_ * (r_ + 1)) >> 1);
    }
    const int  r0   = rb2 << 3;
    const int  j0q  = cb2 << 1;          // global col-quad base
    const bool diag = (rb2 == cb2);
    int rowQ[8];
    #pragma unroll
    for (int s2 = 0; s2 < 8; ++s2) rowQ[s2] = rowoff(r0 + s2) >> 2;
    const int pq0 = physq(j0q), pq1 = physq(j0q + 1);

    // --- load lower triangle of M = Q + I by region ---
    if (t < NREG) {
        #pragma unroll
        for (int s2 = 0; s2 < 8; ++s2) {
            const int r = r0 + s2;
            #pragma unroll
            for (int h = 0; h < 2; ++h) {
                if (diag && h == 1 && s2 < 4) continue;   // upper quad
                const int gq = j0q + h;
                float4 v = *(const float4*)(Q + qbase + ((size_t)r << 8) + (gq << 2));
                if (diag) {
                    const int c0 = gq << 2;
                    v.x = (c0 + 0 > r) ? 0.f : (v.x + (c0 + 0 == r ? 1.f : 0.f));
                    v.y = (c0 + 1 > r) ? 0.f : (v.y + (c0 + 1 == r ? 1.f : 0.f));
                    v.z = (c0 + 2 > r) ? 0.f : (v.z + (c0 + 2 == r ? 1.f : 0.f));
                    v.w = (c0 + 3 > r) ? 0.f : (v.w + (c0 + 3 == r ? 1.f : 0.f));
                }
                tri4[rowQ[s2] + gq] = v;
            }
        }
    }
    __syncthreads();

    // --- per-thread constants for phase 1 / 2 ---
    const int i1     = t >> 1;               // phase-1 row (t < 512)
    const int h1     = t & 1;
    const int rowQi1 = (i1 < NX) ? (rowoff(i1) >> 2) : 0;
    const int pfi1   = physf(i1 & 255);
    const int pfT    = physf(t & 255);       // phase-2 (t < 256)

    // --- rank-8 blocked sweep: 32 steps; tri becomes -(M^{-1}) ---
    for (int kb = 0; kb < 32; ++kb) {
        const int k0 = kb << 3;

        // phase 1: snapshot panel P[i][0..7] -> PT (transposed, swizzled)
        if (t < 512) {
            const int i = i1;
            float v0, v1, v2, v3;
            if (i >= k0 + 8) {
                float4 v = tri4[rowQi1 + (kb << 1) + h1];
                v0 = v.x; v1 = v.y; v2 = v.z; v3 = v.w;
            } else {
                const int roi = rowoff(i);
                {   int km = k0 + (h1 << 2) + 0;
                    v0 = (km <= i) ? tri[roi + km] : tri[rowoff(km) + i]; }
                {   int km = k0 + (h1 << 2) + 1;
                    v1 = (km <= i) ? tri[roi + km] : tri[rowoff(km) + i]; }
                {   int km = k0 + (h1 << 2) + 2;
                    v2 = (km <= i) ? tri[roi + km] : tri[rowoff(km) + i]; }
                {   int km = k0 + (h1 << 2) + 3;
                    v3 = (km <= i) ? tri[roi + km] : tri[rowoff(km) + i]; }
            }
            const int rbase = (h1 << 2) * PTF + pfi1;
            PT[rbase + 0 * PTF] = v0;
            PT[rbase + 1 * PTF] = v1;
            PT[rbase + 2 * PTF] = v2;
            PT[rbase + 3 * PTF] = v3;
        }
        __syncthreads();

        // phase 1.5: wave 0 sweeps the 8x8 pivot block in-register -> SL
        if (t < 64) {
            const int a = t >> 3, bb = t & 7;
            float S = PT[bb * PTF + physf(k0 + a)];   // D[a][b] (symmetric)
            #pragma unroll
            for (int kk = 0; kk < 8; ++kk) {
                const float dkk = __shfl(S, kk * 9);
                const float inv = 1.0f / dkk;
                const float cs  = __shfl(S, (t & 56) | kk);   // S[a][kk]
                const float rs  = __shfl(S, (kk << 3) | bb);  // S[kk][b]
                const float upd = S - cs * rs * inv;
                const bool ad = (a == kk), bd = (bb == kk);
                S = (ad && bd) ? -inv : (ad ? rs * inv : (bd ? cs * inv : upd));
            }
            SL[a * 9 + bb] = S;
        }
        __syncthreads();

        // phase 2: t<256 computes W[i][:] = -(P[i]·S) -> WT (transposed) + W8
        if (t < 256) {
            float pv[8];
            #pragma unroll
            for (int m = 0; m < 8; ++m) pv[m] = PT[m * PTF + pfT];
            float w[8];
            #pragma unroll
            for (int c = 0; c < 8; ++c) {
                float acc = 0.f;
                #pragma unroll
                for (int m = 0; m < 8; ++m) acc += pv[m] * SL[m * 9 + c];
                w[c] = -acc;
                WT[c * PTF + t] = -acc;
            }
            *(float4*)(W8 + (t << 3))     = make_float4(w[0], w[1], w[2], w[3]);
            *(float4*)(W8 + (t << 3) + 4) = make_float4(w[4], w[5], w[6], w[7]);
        }
        __syncthreads();

        // phase 3: per-region update
        if (t < NREG) {
            if (rb2 == kb) {
                if (cb2 == kb) {            // pivot block: A[K][K] = S
                    #pragma unroll
                    for (int s2 = 0; s2 < 8; ++s2) {
                        #pragma unroll
                        for (int h = 0; h < 2; ++h) {
                            if (h == 1 && s2 < 4) continue;
                            const int c4 = (h << 2);
                            float4 v = make_float4(SL[s2 * 9 + c4 + 0], SL[s2 * 9 + c4 + 1],
                                                   SL[s2 * 9 + c4 + 2], SL[s2 * 9 + c4 + 3]);
                            tri4[rowQ[s2] + j0q + h] = v;
                        }
                    }
                } else {                    // pivot rows: A[k0+s2][j] = W[j][s2]
                    #pragma unroll
                    for (int s2 = 0; s2 < 8; ++s2) {
                        float4 wv0 = *(const float4*)(WT + s2 * PTF + (j0q << 2));
                        float4 wv1 = *(const float4*)(WT + s2 * PTF + (j0q << 2) + 4);
                        tri4[rowQ[s2] + j0q + 0] = wv0;
                        tri4[rowQ[s2] + j0q + 1] = wv1;
                    }
                }
            } else if (cb2 == kb) {         // panel: A[r][K] = W[r][0..7]
                #pragma unroll
                for (int s2 = 0; s2 < 8; ++s2) {
                    const int r = r0 + s2;
                    tri4[rowQ[s2] + j0q + 0] = *(const float4*)(W8 + (r << 3));
                    tri4[rowQ[s2] + j0q + 1] = *(const float4*)(W8 + (r << 3) + 4);
                }
            } else {                        // Schur: A -= W * P^T
                float4 acc[8][2];
                #pragma unroll
                for (int s2 = 0; s2 < 8; ++s2) {
                    acc[s2][0] = tri4[rowQ[s2] + j0q + 0];
                    acc[s2][1] = tri4[rowQ[s2] + j0q + 1];
                }
                #pragma unroll
                for (int m = 0; m < 8; ++m) {
                    const float4 pa = *(const float4*)(PT + m * PTF + (pq0 << 2));
                    const float4 pb = *(const float4*)(PT + m * PTF + (pq1 << 2));
                    const float4 wa = *(const float4*)(WT + m * PTF + (rb2 << 3));
                    const float4 wb = *(const float4*)(WT + m * PTF + (rb2 << 3) + 4);
                    const float ws[8] = {wa.x, wa.y, wa.z, wa.w, wb.x, wb.y, wb.z, wb.w};
                    #pragma unroll
                    for (int s2 = 0; s2 < 8; ++s2) {
                        acc[s2][0].x -= ws[s2] * pa.x;
                        acc[s2][0].y -= ws[s2] * pa.y;
                        acc[s2][0].z -= ws[s2] * pa.z;
                        acc[s2][0].w -= ws[s2] * pa.w;
                        acc[s2][1].x -= ws[s2] * pb.x;
                        acc[s2][1].y -= ws[s2] * pb.y;
                        acc[s2][1].z -= ws[s2] * pb.z;
                        acc[s2][1].w -= ws[s2] * pb.w;
                    }
                }
                #pragma unroll
                for (int s2 = 0; s2 < 8; ++s2) {
                    tri4[rowQ[s2] + j0q + 0] = acc[s2][0];
                    if (!(diag && s2 < 4)) tri4[rowQ[s2] + j0q + 1] = acc[s2][1];
                }
            }
        }
        __syncthreads();
    }

    // --- expand Minv row chunk into pinned registers ---
    const int rr = t >> 2, q4 = t & 3;
    const int jc = q4 << 6;
    float mr[64];
    {
        const int offr = rowoff(rr);
        #pragma unroll
        for (int jj = 0; jj < 64; ++jj) {
            const int j = jc + jj;
            const int addr = (j <= rr) ? (offr + j) : (rowoff(j) + rr);
            mr[jj] = tri[addr];   // = -Minv[rr][j]
        }
    }
    #pragma unroll
    for (int jj = 0; jj < 64; ++jj) asm volatile("" : "+v"(mr[jj]));

    const int gb = (b << 8) + rr;
    const float pi = p[gb], lbi = lb[gb], ubi = ub[gb];
    const int vw = rr + ((rr >> 6) << 2);   // padded rhs slot (stride-68 chunks)

    float x = 0.f, z = 0.f, u = 0.f;
    __syncthreads();
    for (int it = 0; it < NITER; ++it) {
        if (q4 == 0) vbuf[vw] = (u + pi) - z;   // vbuf = -(rhs)
        __syncthreads();
        const float4* vb4 = (const float4*)(vbuf + q4 * 68);
        float a0 = 0.f, a1 = 0.f, a2 = 0.f, a3 = 0.f;
        #pragma unroll
        for (int m = 0; m < 16; ++m) {
            const float4 v = vb4[m];
            a0 += mr[4 * m + 0] * v.x;
            a1 += mr[4 * m + 1] * v.y;
            a2 += mr[4 * m + 2] * v.z;
            a3 += mr[4 * m + 3] * v.w;
        }
        float s = (a0 + a1) + (a2 + a3);
        s += __shfl_xor(s, 1);
        s += __shfl_xor(s, 2);
        x = s;                                   // x = Minv * rhs
        const float xu = x + u;
        z = fminf(fmaxf(xu, lbi), ubi);
        u = xu - z;
        __syncthreads();
    }

    if (q4 == 0) out[gb] = x;
}

extern "C" void kernel_launch(void* const* d_in, const int* in_sizes, int n_in,
                              void* d_out, int out_size, void* d_ws, size_t ws_size,
                              hipStream_t stream) {
    const float* Q  = (const float*)d_in[0];
    const float* p  = (const float*)d_in[1];
    const float* lb = (const float*)d_in[2];
    const float* ub = (const float*)d_in[3];
    float* out = (float*)d_out;

    const size_t shmem = (size_t)LDS_F * 4;   // 159616 B
    (void)hipFuncSetAttribute((const void*)boxqp_r8_kernel,
                              hipFuncAttributeMaxDynamicSharedMemorySize,
                              (int)shmem);

    hipLaunchKernelGGL(boxqp_r8_kernel, dim3(256), dim3(NTHR), shmem, stream,
                       Q, p, lb, ub, out);
}